// Round 3
// baseline (7662.479 us; speedup 1.0000x reference)
//
#include <hip/hip_runtime.h>
#include <hip/hip_bf16.h>
#include <stdint.h>

#define F_N 64
#define T_N 256
#define B_N 64
#define H_N 512
// W partition: ks 0..7 streamed (VGPR rotation), ks 8..13 VGPR-static, ks 14..15 LDS-static
#define STREAM_KS 8
#define VREG_KS0 8
#define NVSTAT 6
#define LDS_KS0 14
// L2 pinning: streamed ks < NT_KS loaded non-temporal (LRU-first, no pollution);
// ks NT_KS..7 loaded normal -> 3 units x 32KB x 32 blocks = 3 MB/XCD stays L2-resident
// across steps and becomes a deterministic per-step hit.
#define NT_KS 5

typedef __attribute__((ext_vector_type(8))) __bf16 bf16x8;
typedef __attribute__((ext_vector_type(4))) float f32x4;
typedef __attribute__((ext_vector_type(4))) uint32_t u32x4;

__device__ __forceinline__ bf16x8 ldg_nt(const bf16x8* p) {
  u32x4 r = __builtin_nontemporal_load((const u32x4*)p);
  union { u32x4 u; bf16x8 b; } cv;
  cv.u = r;
  return cv.b;
}
__device__ __forceinline__ u32x4 ldg_nt_u(const void* p) {
  return __builtin_nontemporal_load((const u32x4*)p);
}

// ---------------- pack kernels ----------------

__global__ void pack_x_kernel(const float* __restrict__ tf, const float* __restrict__ tm,
                              float* __restrict__ xp) {
  int tid = blockIdx.x * 256 + threadIdx.x;
  if (tid >= T_N * B_N * F_N) return;
  int f = tid & 63;
  int b = (tid >> 6) & 63;
  int t = tid >> 12;
  float v = tf[((size_t)b * T_N + t) * F_N + f];
  float m = tm[((size_t)b * T_N + t) * F_N + f];
  float* dst = xp + (((size_t)t * F_N + f) * B_N + b) * 2;
  dst[0] = v;
  dst[1] = m;
}

__global__ void pack_h0_kernel(const float* __restrict__ h0, __bf16* __restrict__ hx0) {
  int tid = blockIdx.x * 256 + threadIdx.x;
  if (tid < F_N * B_N * H_N) hx0[tid] = (__bf16)h0[tid];
}

// Whh fp32 [F][2048][512] -> Wp bf16 in MFMA B-fragment order.
// gtid = f<<17 | q<<15 | w<<12 | ks<<8 | nt<<6 | lane ; 16 B per gtid.
// Lane holds B[k = ks*32 + (lane>>4)*8 + j][col = lane&15],
// B[k][n] = W[grow(n)][k], n = w*64 + nt*16 + (lane&15),
// grow = (n&3)*512 + q*128 + (n>>2).
__global__ void pack_w_kernel(const float* __restrict__ Whh, __bf16* __restrict__ Wp) {
  int gtid = blockIdx.x * 256 + threadIdx.x;  // 8,388,608 total
  int lane = gtid & 63;
  int nt = (gtid >> 6) & 3;
  int ks = (gtid >> 8) & 15;
  int w = (gtid >> 12) & 7;
  int q = (gtid >> 15) & 3;
  int f = gtid >> 17;
  int l15 = lane & 15, lhi = lane >> 4;
  int n_local = w * 64 + nt * 16 + l15;
  int r_local = n_local >> 2;
  int gam = n_local & 3;
  int grow = gam * 512 + q * 128 + r_local;
  const float* src = Whh + ((size_t)f * 2048 + grow) * 512 + ks * 32 + lhi * 8;
  float4 u0 = *(const float4*)src;
  float4 u1 = *(const float4*)(src + 4);
  bf16x8 v;
  v[0] = (__bf16)u0.x; v[1] = (__bf16)u0.y; v[2] = (__bf16)u0.z; v[3] = (__bf16)u0.w;
  v[4] = (__bf16)u1.x; v[5] = (__bf16)u1.y; v[6] = (__bf16)u1.z; v[7] = (__bf16)u1.w;
  *(bf16x8*)((char*)Wp + (size_t)gtid * 16) = v;
}

// ---------------- main persistent kernel ----------------
// grid 256 x 512 (1 block/CU by LDS -> 2 waves/SIMD; amdgpu_waves_per_eu(2,2)).
// R0-R2 lesson: dur ~= FETCH_SIZE / 2.2-2.4 TB/s; request-byte reduction didn't
// move misses (L2 hit fraction is accidental LRU survival). This round: make
// survival deterministic. Streamed ks0..4 loaded non-temporal (evict-first);
// ks5..7 loaded normal and re-touched every step -> pinned L2-resident (3 MB/XCD).
// Partner-h stage reads also nt (read-once lines, stop competing with pinned W).
// Otherwise byte-identical to R2.

__global__ void __launch_bounds__(512, 1) __attribute__((amdgpu_waves_per_eu(2, 2)))
lstm_main(
    const float* __restrict__ c0, const __bf16* __restrict__ Wp,
    const float* __restrict__ Wih, const float* __restrict__ bih,
    const float* __restrict__ bhh, const float* __restrict__ xp,
    __bf16* hx, unsigned int* barr, unsigned int* xcdmap, float* __restrict__ out) {
  const int blk = blockIdx.x;
  const int f = blk & 63;
  const int q = blk >> 6;
  const int tid = threadIdx.x;  // 0..511
  const int lane = tid & 63;
  const int w = tid >> 6;  // 0..7
  const int l15 = lane & 15;
  const int lhi = lane >> 4;
  const int ls = lane & 3;
  const int lr = l15 >> 2;

  __shared__ __align__(16) unsigned char lds_h[65536];      // h bf16 [64][512], swizzled rows
  __shared__ __align__(16) unsigned char lds_stage[16384];  // own h slice [64][128], swizzled
  __shared__ __align__(16) unsigned char lds_wst[65536];    // W ks 14,15: [2][8][4][64]x16B
  __shared__ __align__(16) float ldsB[512];
  __shared__ __align__(16) float lds0[512];
  __shared__ __align__(16) float lds1[512];
  __shared__ int s_same;

  // tables (fp32, exact): i = r*4 + gamma
  {
    int i = tid;
    int r = i >> 2, g = i & 3;
    int row = g * 512 + q * 128 + r;
    size_t ro = (size_t)f * 2048 + row;
    ldsB[i] = bih[ro] + bhh[ro];
    lds0[i] = Wih[ro * 2 + 0];
    lds1[i] = Wih[ro * 2 + 1];
  }

  // ---- one-time XCD-placement handshake (tid 0) ----
  if (tid == 0) {
    uint32_t xcc;
    asm volatile("s_getreg_b32 %0, hwreg(HW_REG_XCC_ID)" : "=s"(xcc));
    xcc &= 15u;
    __hip_atomic_store(&xcdmap[f * 4 + q], xcc + 1u, __ATOMIC_RELAXED,
                       __HIP_MEMORY_SCOPE_AGENT);
    uint32_t ids[4];
    int ok = 1;
    for (int j = 0; j < 4; ++j) {
      unsigned int it = 0;
      uint32_t v;
      do {
        v = __hip_atomic_load(&xcdmap[f * 4 + j], __ATOMIC_RELAXED,
                              __HIP_MEMORY_SCOPE_AGENT);
        if (++it > 2000000u) { ok = 0; break; }
        if (v == 0u) __builtin_amdgcn_s_sleep(2);
      } while (v == 0u);
      ids[j] = v;
    }
    if (ok) ok = (ids[0] == ids[1]) & (ids[1] == ids[2]) & (ids[2] == ids[3]);
    s_same = ok;
  }

  const bf16x8* wpbase = (const bf16x8*)Wp + ((size_t)((f * 4 + q) * 8 + w)) * 4096 + lane;

  // streamed-W rotation: 3 slots x 4 nt (48 VGPRs); ks < NT_KS non-temporal
  bf16x8 s[3][4];
#define LOAD_SLOT(SL, KS)                                                   \
  {                                                                         \
    _Pragma("unroll") for (int nt_ = 0; nt_ < 4; ++nt_) {                   \
      const bf16x8* p_ = wpbase + ((KS) * 4 + nt_) * 64;                    \
      s[SL][nt_] = ((KS) < NT_KS) ? ldg_nt(p_) : *p_;                       \
    }                                                                       \
  }

  // ---- VGPR-static W: ks 8..13 (96 VGPRs, loaded once) ----
  bf16x8 wsf[NVSTAT][4];
#pragma unroll
  for (int s2 = 0; s2 < NVSTAT; ++s2)
#pragma unroll
    for (int nt = 0; nt < 4; ++nt) wsf[s2][nt] = wpbase[((VREG_KS0 + s2) * 4 + nt) * 64];

  // ---- LDS-static W: ks 14,15 ----
#pragma unroll
  for (int ksi = 0; ksi < 2; ++ksi)
#pragma unroll
    for (int nt = 0; nt < 4; ++nt) {
      bf16x8 v = wpbase[((LDS_KS0 + ksi) * 4 + nt) * 64];
      *(bf16x8*)(lds_wst + (((ksi * 8 + w) * 4 + nt) << 10) + lane * 16) = v;
    }

  // cell state
  float c_reg[4][4];
#pragma unroll
  for (int mt = 0; mt < 4; ++mt) {
    int brow = mt * 16 + lhi * 4 + ls;
#pragma unroll
    for (int nt = 0; nt < 4; ++nt) {
      int rg = w * 16 + nt * 4 + lr;
      c_reg[mt][nt] = c0[((size_t)f * B_N + brow) * H_N + q * 128 + rg];
    }
  }

  const size_t hxfeat = (size_t)f * (B_N * H_N);
  const size_t hxstride = (size_t)F_N * B_N * H_N;

  // ---- initial full h stage into lds_h ----
  {
    const unsigned char* src = (const unsigned char*)(hx + hxfeat);
    uint32_t b = tid >> 3;
    uint32_t off = (tid & 7) * 32;
    uint32_t sw = (b & 7) << 4;
#pragma unroll
    for (int qq = 0; qq < 4; ++qq) {
      uint32_t gb = b * 1024 + qq * 256 + off;
      uint4 u0 = *(const uint4*)(src + gb);
      uint4 u1 = *(const uint4*)(src + gb + 16);
      *(uint4*)(lds_h + (gb ^ sw)) = u0;
      *(uint4*)(lds_h + ((gb + 16) ^ sw)) = u1;
    }
  }
  LOAD_SLOT(0, 0);
  LOAD_SLOT(1, 1);
  LOAD_SLOT(2, 2);
  __syncthreads();
  const bool fastpath = (s_same != 0);

  // per-K-unit building blocks (a[] is shared scratch; acc chain enforces order)
#define READ_A(KS)                                                                     \
  {                                                                                    \
    _Pragma("unroll") for (int mt = 0; mt < 4; ++mt) {                                 \
      int row = mt * 16 + l15;                                                         \
      uint32_t byteoff =                                                               \
          (uint32_t)(row * 1024) + (((uint32_t)((KS) * 64 + lhi * 16)) ^ ((row & 7) << 4)); \
      a[mt] = *(const bf16x8*)(lds_h + byteoff);                                       \
    }                                                                                  \
  }
#define MFMA_W(WARR)                                                                   \
  {                                                                                    \
    _Pragma("unroll") for (int mt = 0; mt < 4; ++mt)                                   \
        _Pragma("unroll") for (int nt = 0; nt < 4; ++nt)                               \
            acc[mt][nt] = __builtin_amdgcn_mfma_f32_16x16x32_bf16(a[mt], (WARR)[nt],   \
                                                                  acc[mt][nt], 0, 0, 0); \
  }
#define STATIC_V(S2) { READ_A(VREG_KS0 + (S2)); MFMA_W(wsf[S2]); }
#define STATIC_L(KSI)                                                                  \
  {                                                                                    \
    READ_A(LDS_KS0 + (KSI));                                                           \
    bf16x8 wfrag[4];                                                                   \
    _Pragma("unroll") for (int nt = 0; nt < 4; ++nt) wfrag[nt] =                       \
        *(const bf16x8*)(lds_wst + ((((KSI) * 8 + w) * 4 + nt) << 10) + lane * 16);    \
    MFMA_W(wfrag);                                                                     \
  }
#define STREAM(KS)                                                                     \
  {                                                                                    \
    READ_A(KS);                                                                        \
    MFMA_W(s[(KS) % 3]);                                                               \
    if ((KS) + 3 < STREAM_KS) {                                                        \
      _Pragma("unroll") for (int nt_ = 0; nt_ < 4; ++nt_) {                            \
        const bf16x8* p_ = wpbase + (((KS) + 3) * 4 + nt_) * 64;                       \
        s[(KS) % 3][nt_] = (((KS) + 3) < NT_KS) ? ldg_nt(p_) : *p_;                    \
      }                                                                                \
    }                                                                                  \
  }

#pragma unroll 1
  for (int t = 0; t < T_N; ++t) {
    f32x4 acc[4][4] = {};
    bf16x8 a[4];

    // ---- interleaved K-units: static blocks give each streamed wait latency cover ----
    STATIC_V(0); STREAM(0);
    STATIC_V(1); STREAM(1);
    STATIC_V(2); STREAM(2);
    STATIC_V(3); STREAM(3);
    STATIC_V(4); STREAM(4);
    STATIC_V(5); STREAM(5);
    STATIC_L(0); STREAM(6);
    STATIC_L(1); STREAM(7);

    // ---- epilogue (fp32) ----
    const bool last = (t == T_N - 1);
    const float* xpt = xp + (((size_t)t * F_N + f) * B_N) * 2;
#pragma unroll
    for (int mt = 0; mt < 4; ++mt) {
      int brow = mt * 16 + lhi * 4 + ls;
      float xv = xpt[brow * 2];
      float xm = xpt[brow * 2 + 1];
#pragma unroll
      for (int nt = 0; nt < 4; ++nt) {
        float v0 = acc[mt][nt][0], v1 = acc[mt][nt][1], v2 = acc[mt][nt][2], v3 = acc[mt][nt][3];
        {
          float t0 = __shfl_xor(v0, 1), t1 = __shfl_xor(v1, 1),
                t2 = __shfl_xor(v2, 1), t3 = __shfl_xor(v3, 1);
          if (lane & 1) { v0 = t1; v2 = t3; } else { v1 = t0; v3 = t2; }
        }
        {
          float t0 = __shfl_xor(v0, 2), t1 = __shfl_xor(v1, 2),
                t2 = __shfl_xor(v2, 2), t3 = __shfl_xor(v3, 2);
          if (lane & 2) { v0 = t2; v1 = t3; } else { v2 = t0; v3 = t1; }
        }
        int rg = w * 16 + nt * 4 + lr;
        int idx4 = rg << 2;
        float4 tb = *(const float4*)&ldsB[idx4];
        float4 w0t = *(const float4*)&lds0[idx4];
        float4 w1t = *(const float4*)&lds1[idx4];
        v0 += tb.x + w0t.x * xv + w1t.x * xm;
        v1 += tb.y + w0t.y * xv + w1t.y * xm;
        v2 += tb.z + w0t.z * xv + w1t.z * xm;
        v3 += tb.w + w0t.w * xv + w1t.w * xm;
        float ig = __builtin_amdgcn_rcpf(1.0f + __expf(-v0));
        float fg = __builtin_amdgcn_rcpf(1.0f + __expf(-v1));
        float gg = 2.0f * __builtin_amdgcn_rcpf(1.0f + __expf(-2.0f * v2)) - 1.0f;
        float og = __builtin_amdgcn_rcpf(1.0f + __expf(-v3));
        float cn = fg * c_reg[mt][nt] + ig * gg;
        c_reg[mt][nt] = cn;
        float th = 2.0f * __builtin_amdgcn_rcpf(1.0f + __expf(-2.0f * cn)) - 1.0f;
        float hn = og * th;
        if (last) {
          out[((size_t)f * B_N + brow) * H_N + q * 128 + rg] = hn;
        } else {
          uint32_t sw = (uint32_t)((brow & 7) << 4);
          *(__bf16*)(lds_stage + ((uint32_t)(brow * 256 + rg * 2) ^ sw)) = (__bf16)hn;
        }
      }
    }
    if (last) break;

    __syncthreads();  // lds_stage complete; all lds_h reads done

    // ---- publish own slice (16 KB) + write it into lds_h own quarter ----
    {
      __bf16* dstbuf = hx + ((size_t)((t + 1) & 1)) * hxstride + hxfeat;
      uint32_t b = tid >> 3;
      uint32_t off = (tid & 7) * 32;
      uint32_t sw = (b & 7) << 4;
      u32x4 u0 = *(const u32x4*)(lds_stage + ((b * 256 + off) ^ sw));
      u32x4 u1 = *(const u32x4*)(lds_stage + ((b * 256 + off + 16) ^ sw));
      unsigned char* dp = (unsigned char*)dstbuf + b * 1024 + q * 256 + off;
      if (fastpath) {
        asm volatile("global_store_dwordx4 %0, %1, off sc0" ::"v"(dp), "v"(u0) : "memory");
        asm volatile("global_store_dwordx4 %0, %1, off sc0" ::"v"(dp + 16), "v"(u1) : "memory");
        asm volatile("s_waitcnt vmcnt(0)" ::: "memory");
      } else {
        *(u32x4*)(dp) = u0;
        *(u32x4*)(dp + 16) = u1;
      }
      uint32_t hb = b * 1024 + q * 256 + off;
      *(u32x4*)(lds_h + (hb ^ sw)) = u0;
      *(u32x4*)(lds_h + ((hb + 16) ^ sw)) = u1;
    }
    __syncthreads();  // all publishes drained to L2

    // ---- 4-WG rendezvous; next step's streamed prologue overlaps the wait ----
    if (tid == 0) {
      unsigned int* bp = barr + f * T_N + t;
      if (fastpath)
        __hip_atomic_fetch_add(bp, 1u, __ATOMIC_RELAXED, __HIP_MEMORY_SCOPE_AGENT);
      else
        __hip_atomic_fetch_add(bp, 1u, __ATOMIC_RELEASE, __HIP_MEMORY_SCOPE_AGENT);
    }
    LOAD_SLOT(0, 0);
    LOAD_SLOT(1, 1);
    LOAD_SLOT(2, 2);
    if (tid == 0) {
      unsigned int* bp = barr + f * T_N + t;
      unsigned int it = 0;
      while (__hip_atomic_load(bp, __ATOMIC_RELAXED, __HIP_MEMORY_SCOPE_AGENT) < 4u) {
        __builtin_amdgcn_s_sleep(1);
        if (++it > 4000000u) break;  // bail -> wrong answer instead of hang
      }
      if (!fastpath)
        (void)__hip_atomic_load(bp, __ATOMIC_ACQUIRE, __HIP_MEMORY_SCOPE_AGENT);
    }
    __syncthreads();

    // ---- stage the 3 partner quarters (48 KB) into lds_h, non-temporal reads ----
    if (fastpath) {
      asm volatile("buffer_inv sc0" ::: "memory");  // vL1-only invalidate
    }
    {
      const unsigned char* src =
          (const unsigned char*)(hx + ((size_t)((t + 1) & 1)) * hxstride + hxfeat);
      uint32_t b = tid >> 3;
      uint32_t off = (tid & 7) * 32;
      uint32_t sw = (b & 7) << 4;
#pragma unroll
      for (int qq = 0; qq < 4; ++qq) {
        if (qq == q) continue;
        uint32_t gb = b * 1024 + qq * 256 + off;
        u32x4 u0 = ldg_nt_u(src + gb);
        u32x4 u1 = ldg_nt_u(src + gb + 16);
        *(u32x4*)(lds_h + (gb ^ sw)) = u0;
        *(u32x4*)(lds_h + ((gb + 16) ^ sw)) = u1;
      }
    }
    __syncthreads();
  }
#undef LOAD_SLOT
#undef READ_A
#undef MFMA_W
#undef STATIC_V
#undef STATIC_L
#undef STREAM
}

// ---------------- launch ----------------
extern "C" void kernel_launch(void* const* d_in, const int* in_sizes, int n_in,
                              void* d_out, int out_size, void* d_ws, size_t ws_size,
                              hipStream_t stream) {
  const float* tf = (const float*)d_in[0];
  const float* tm = (const float*)d_in[1];
  const float* h0 = (const float*)d_in[2];
  const float* c0 = (const float*)d_in[3];
  const float* Wih = (const float*)d_in[4];
  const float* Whh = (const float*)d_in[5];
  const float* bih = (const float*)d_in[6];
  const float* bhh = (const float*)d_in[7];
  float* out = (float*)d_out;

  const size_t WP_BYTES = (size_t)8388608 * 16;             // 134,217,728
  const size_t XP_BYTES = (size_t)T_N * F_N * B_N * 2 * 4;  // 16,777,216
  const size_t HX_BYTES = (size_t)2 * F_N * B_N * H_N * 2;  // 8,388,608
  const size_t BARR_BYTES = (size_t)F_N * T_N * 4;          // 65,536
  const size_t MAP_BYTES = 1024;
  if (ws_size < WP_BYTES + XP_BYTES + HX_BYTES + BARR_BYTES + MAP_BYTES) return;

  char* ws = (char*)d_ws;
  __bf16* Wp = (__bf16*)ws;
  float* xp = (float*)(ws + WP_BYTES);
  __bf16* hx = (__bf16*)(ws + WP_BYTES + XP_BYTES);
  unsigned int* barr = (unsigned int*)(ws + WP_BYTES + XP_BYTES + HX_BYTES);
  unsigned int* xcdmap = (unsigned int*)(ws + WP_BYTES + XP_BYTES + HX_BYTES + BARR_BYTES);

  hipMemsetAsync(barr, 0, BARR_BYTES + MAP_BYTES, stream);
  pack_x_kernel<<<(T_N * B_N * F_N + 255) / 256, 256, 0, stream>>>(tf, tm, xp);
  pack_h0_kernel<<<(F_N * B_N * H_N + 255) / 256, 256, 0, stream>>>(h0, hx);
  pack_w_kernel<<<8388608 / 256, 256, 0, stream>>>(Whh, Wp);
  lstm_main<<<256, 512, 0, stream>>>(c0, Wp, Wih, bih, bhh, xp, hx, barr, xcdmap, out);
}

// Round 4
// 6141.950 us; speedup vs baseline: 1.2476x; 1.2476x over previous
//
#include <hip/hip_runtime.h>
#include <hip/hip_bf16.h>
#include <stdint.h>

#define F_N 64
#define T_N 256
#define B_N 64
#define H_N 512
// W partition: ks 0..7 streamed (VGPR rotation), ks 8..13 VGPR-static, ks 14..15 LDS-static
#define STREAM_KS 8
#define VREG_KS0 8
#define NVSTAT 6
#define LDS_KS0 14

typedef __attribute__((ext_vector_type(8))) __bf16 bf16x8;
typedef __attribute__((ext_vector_type(4))) float f32x4;
typedef __attribute__((ext_vector_type(4))) uint32_t u32x4;

// ---------------- pack kernels ----------------

__global__ void pack_x_kernel(const float* __restrict__ tf, const float* __restrict__ tm,
                              float* __restrict__ xp) {
  int tid = blockIdx.x * 256 + threadIdx.x;
  if (tid >= T_N * B_N * F_N) return;
  int f = tid & 63;
  int b = (tid >> 6) & 63;
  int t = tid >> 12;
  float v = tf[((size_t)b * T_N + t) * F_N + f];
  float m = tm[((size_t)b * T_N + t) * F_N + f];
  float* dst = xp + (((size_t)t * F_N + f) * B_N + b) * 2;
  dst[0] = v;
  dst[1] = m;
}

__global__ void pack_h0_kernel(const float* __restrict__ h0, __bf16* __restrict__ hx0) {
  int tid = blockIdx.x * 256 + threadIdx.x;
  if (tid < F_N * B_N * H_N) hx0[tid] = (__bf16)h0[tid];
}

// Whh fp32 [F][2048][512] -> Wp bf16 in MFMA B-fragment order.
// gtid = f<<17 | q<<15 | w<<12 | ks<<8 | nt<<6 | lane ; 16 B per gtid.
// Lane holds B[k = ks*32 + (lane>>4)*8 + j][col = lane&15],
// B[k][n] = W[grow(n)][k], n = w*64 + nt*16 + (lane&15),
// grow = (n&3)*512 + q*128 + (n>>2).
__global__ void pack_w_kernel(const float* __restrict__ Whh, __bf16* __restrict__ Wp) {
  int gtid = blockIdx.x * 256 + threadIdx.x;  // 8,388,608 total
  int lane = gtid & 63;
  int nt = (gtid >> 6) & 3;
  int ks = (gtid >> 8) & 15;
  int w = (gtid >> 12) & 7;
  int q = (gtid >> 15) & 3;
  int f = gtid >> 17;
  int l15 = lane & 15, lhi = lane >> 4;
  int n_local = w * 64 + nt * 16 + l15;
  int r_local = n_local >> 2;
  int gam = n_local & 3;
  int grow = gam * 512 + q * 128 + r_local;
  const float* src = Whh + ((size_t)f * 2048 + grow) * 512 + ks * 32 + lhi * 8;
  float4 u0 = *(const float4*)src;
  float4 u1 = *(const float4*)(src + 4);
  bf16x8 v;
  v[0] = (__bf16)u0.x; v[1] = (__bf16)u0.y; v[2] = (__bf16)u0.z; v[3] = (__bf16)u0.w;
  v[4] = (__bf16)u1.x; v[5] = (__bf16)u1.y; v[6] = (__bf16)u1.z; v[7] = (__bf16)u1.w;
  *(bf16x8*)((char*)Wp + (size_t)gtid * 16) = v;
}

// ---------------- main persistent kernel ----------------
// grid 256 x 512 (1 block/CU by LDS -> 2 waves/SIMD; amdgpu_waves_per_eu(2,2)).
// R0-R3 ledger: miss bytes pinned at ~5.8 MB/XCD/step for ANY streamed-request
// volume -> L2 keeps only the most-recently-touched ~4MB/XCD; reading head-first
// each step evicts the survivors before consuming them. THIS ROUND: parity-
// alternating stream order. Even steps read streamed units 0..7; odd steps read
// 4,5,6,7,0,1,2,3 -> each step STARTS with the ~4 units still L2-resident from
// the previous step's tail => deterministic ~50% hit rate, same bytes requested.
// ks(pos) = (pos + 4*(t&1)) & 7. Everything else identical to R2 (nt hints of
// R3 reverted: they increased misses).
// W residency: ks 8..13 static in VGPRs, ks 14..15 static in LDS, ks 0..7
// streamed depth-3 rotation, statics interleaved for latency cover.
// h single-buffered in LDS; exchange protocol unchanged.

__global__ void __launch_bounds__(512, 1) __attribute__((amdgpu_waves_per_eu(2, 2)))
lstm_main(
    const float* __restrict__ c0, const __bf16* __restrict__ Wp,
    const float* __restrict__ Wih, const float* __restrict__ bih,
    const float* __restrict__ bhh, const float* __restrict__ xp,
    __bf16* hx, unsigned int* barr, unsigned int* xcdmap, float* __restrict__ out) {
  const int blk = blockIdx.x;
  const int f = blk & 63;
  const int q = blk >> 6;
  const int tid = threadIdx.x;  // 0..511
  const int lane = tid & 63;
  const int w = tid >> 6;  // 0..7
  const int l15 = lane & 15;
  const int lhi = lane >> 4;
  const int ls = lane & 3;
  const int lr = l15 >> 2;

  __shared__ __align__(16) unsigned char lds_h[65536];      // h bf16 [64][512], swizzled rows
  __shared__ __align__(16) unsigned char lds_stage[16384];  // own h slice [64][128], swizzled
  __shared__ __align__(16) unsigned char lds_wst[65536];    // W ks 14,15: [2][8][4][64]x16B
  __shared__ __align__(16) float ldsB[512];
  __shared__ __align__(16) float lds0[512];
  __shared__ __align__(16) float lds1[512];
  __shared__ int s_same;

  // tables (fp32, exact): i = r*4 + gamma
  {
    int i = tid;
    int r = i >> 2, g = i & 3;
    int row = g * 512 + q * 128 + r;
    size_t ro = (size_t)f * 2048 + row;
    ldsB[i] = bih[ro] + bhh[ro];
    lds0[i] = Wih[ro * 2 + 0];
    lds1[i] = Wih[ro * 2 + 1];
  }

  // ---- one-time XCD-placement handshake (tid 0) ----
  if (tid == 0) {
    uint32_t xcc;
    asm volatile("s_getreg_b32 %0, hwreg(HW_REG_XCC_ID)" : "=s"(xcc));
    xcc &= 15u;
    __hip_atomic_store(&xcdmap[f * 4 + q], xcc + 1u, __ATOMIC_RELAXED,
                       __HIP_MEMORY_SCOPE_AGENT);
    uint32_t ids[4];
    int ok = 1;
    for (int j = 0; j < 4; ++j) {
      unsigned int it = 0;
      uint32_t v;
      do {
        v = __hip_atomic_load(&xcdmap[f * 4 + j], __ATOMIC_RELAXED,
                              __HIP_MEMORY_SCOPE_AGENT);
        if (++it > 2000000u) { ok = 0; break; }
        if (v == 0u) __builtin_amdgcn_s_sleep(2);
      } while (v == 0u);
      ids[j] = v;
    }
    if (ok) ok = (ids[0] == ids[1]) & (ids[1] == ids[2]) & (ids[2] == ids[3]);
    s_same = ok;
  }

  const bf16x8* wpbase = (const bf16x8*)Wp + ((size_t)((f * 4 + q) * 8 + w)) * 4096 + lane;

  // streamed-W rotation: 3 slots x 4 nt (48 VGPRs); slot = position % 3
  bf16x8 s[3][4];
#define LOAD_SLOT(SL, KS)                                       \
  {                                                             \
    _Pragma("unroll") for (int nt_ = 0; nt_ < 4; ++nt_)         \
        s[SL][nt_] = wpbase[((KS) * 4 + nt_) * 64];             \
  }

  // ---- VGPR-static W: ks 8..13 (96 VGPRs, loaded once) ----
  bf16x8 wsf[NVSTAT][4];
#pragma unroll
  for (int s2 = 0; s2 < NVSTAT; ++s2)
#pragma unroll
    for (int nt = 0; nt < 4; ++nt) wsf[s2][nt] = wpbase[((VREG_KS0 + s2) * 4 + nt) * 64];

  // ---- LDS-static W: ks 14,15 ----
#pragma unroll
  for (int ksi = 0; ksi < 2; ++ksi)
#pragma unroll
    for (int nt = 0; nt < 4; ++nt) {
      bf16x8 v = wpbase[((LDS_KS0 + ksi) * 4 + nt) * 64];
      *(bf16x8*)(lds_wst + (((ksi * 8 + w) * 4 + nt) << 10) + lane * 16) = v;
    }

  // cell state
  float c_reg[4][4];
#pragma unroll
  for (int mt = 0; mt < 4; ++mt) {
    int brow = mt * 16 + lhi * 4 + ls;
#pragma unroll
    for (int nt = 0; nt < 4; ++nt) {
      int rg = w * 16 + nt * 4 + lr;
      c_reg[mt][nt] = c0[((size_t)f * B_N + brow) * H_N + q * 128 + rg];
    }
  }

  const size_t hxfeat = (size_t)f * (B_N * H_N);
  const size_t hxstride = (size_t)F_N * B_N * H_N;

  // ---- initial full h stage into lds_h ----
  {
    const unsigned char* src = (const unsigned char*)(hx + hxfeat);
    uint32_t b = tid >> 3;
    uint32_t off = (tid & 7) * 32;
    uint32_t sw = (b & 7) << 4;
#pragma unroll
    for (int qq = 0; qq < 4; ++qq) {
      uint32_t gb = b * 1024 + qq * 256 + off;
      uint4 u0 = *(const uint4*)(src + gb);
      uint4 u1 = *(const uint4*)(src + gb + 16);
      *(uint4*)(lds_h + (gb ^ sw)) = u0;
      *(uint4*)(lds_h + ((gb + 16) ^ sw)) = u1;
    }
  }
  // initial prologue: step 0 is even parity -> order 0,1,2,...
  LOAD_SLOT(0, 0);
  LOAD_SLOT(1, 1);
  LOAD_SLOT(2, 2);
  __syncthreads();
  const bool fastpath = (s_same != 0);

  // per-K-unit building blocks (a[] is shared scratch; acc chain enforces order)
#define READ_A(KS)                                                                     \
  {                                                                                    \
    _Pragma("unroll") for (int mt = 0; mt < 4; ++mt) {                                 \
      int row = mt * 16 + l15;                                                         \
      uint32_t byteoff =                                                               \
          (uint32_t)(row * 1024) + (((uint32_t)((KS) * 64 + lhi * 16)) ^ ((row & 7) << 4)); \
      a[mt] = *(const bf16x8*)(lds_h + byteoff);                                       \
    }                                                                                  \
  }
#define MFMA_W(WARR)                                                                   \
  {                                                                                    \
    _Pragma("unroll") for (int mt = 0; mt < 4; ++mt)                                   \
        _Pragma("unroll") for (int nt = 0; nt < 4; ++nt)                               \
            acc[mt][nt] = __builtin_amdgcn_mfma_f32_16x16x32_bf16(a[mt], (WARR)[nt],   \
                                                                  acc[mt][nt], 0, 0, 0); \
  }
#define STATIC_V(S2) { READ_A(VREG_KS0 + (S2)); MFMA_W(wsf[S2]); }
#define STATIC_L(KSI)                                                                  \
  {                                                                                    \
    READ_A(LDS_KS0 + (KSI));                                                           \
    bf16x8 wfrag[4];                                                                   \
    _Pragma("unroll") for (int nt = 0; nt < 4; ++nt) wfrag[nt] =                       \
        *(const bf16x8*)(lds_wst + ((((KSI) * 8 + w) * 4 + nt) << 10) + lane * 16);    \
    MFMA_W(wfrag);                                                                     \
  }
// streamed unit at schedule POSITION POS; actual k-unit = (POS + par4) & 7.
// par4 = 4*(t&1): odd steps start with the previous step's L2-resident tail.
#define STREAM(POS)                                                                    \
  {                                                                                    \
    const int ks_ = ((POS) + par4) & 7;                                                \
    READ_A(ks_);                                                                       \
    MFMA_W(s[(POS) % 3]);                                                              \
    if ((POS) + 3 < STREAM_KS) {                                                       \
      const int ksn_ = ((POS) + 3 + par4) & 7;                                         \
      _Pragma("unroll") for (int nt_ = 0; nt_ < 4; ++nt_)                              \
          s[(POS) % 3][nt_] = wpbase[(ksn_ * 4 + nt_) * 64];                           \
    }                                                                                  \
  }

#pragma unroll 1
  for (int t = 0; t < T_N; ++t) {
    const int par4 = (t & 1) << 2;        // this step's stream-order rotation
    const int par4n = ((t + 1) & 1) << 2; // next step's (for the prologue)
    f32x4 acc[4][4] = {};
    bf16x8 a[4];

    // ---- interleaved K-units: static blocks give each streamed wait latency cover ----
    STATIC_V(0); STREAM(0);
    STATIC_V(1); STREAM(1);
    STATIC_V(2); STREAM(2);
    STATIC_V(3); STREAM(3);
    STATIC_V(4); STREAM(4);
    STATIC_V(5); STREAM(5);
    STATIC_L(0); STREAM(6);
    STATIC_L(1); STREAM(7);

    // ---- epilogue (fp32) ----
    const bool last = (t == T_N - 1);
    const float* xpt = xp + (((size_t)t * F_N + f) * B_N) * 2;
#pragma unroll
    for (int mt = 0; mt < 4; ++mt) {
      int brow = mt * 16 + lhi * 4 + ls;
      float xv = xpt[brow * 2];
      float xm = xpt[brow * 2 + 1];
#pragma unroll
      for (int nt = 0; nt < 4; ++nt) {
        float v0 = acc[mt][nt][0], v1 = acc[mt][nt][1], v2 = acc[mt][nt][2], v3 = acc[mt][nt][3];
        {
          float t0 = __shfl_xor(v0, 1), t1 = __shfl_xor(v1, 1),
                t2 = __shfl_xor(v2, 1), t3 = __shfl_xor(v3, 1);
          if (lane & 1) { v0 = t1; v2 = t3; } else { v1 = t0; v3 = t2; }
        }
        {
          float t0 = __shfl_xor(v0, 2), t1 = __shfl_xor(v1, 2),
                t2 = __shfl_xor(v2, 2), t3 = __shfl_xor(v3, 2);
          if (lane & 2) { v0 = t2; v1 = t3; } else { v2 = t0; v3 = t1; }
        }
        int rg = w * 16 + nt * 4 + lr;
        int idx4 = rg << 2;
        float4 tb = *(const float4*)&ldsB[idx4];
        float4 w0t = *(const float4*)&lds0[idx4];
        float4 w1t = *(const float4*)&lds1[idx4];
        v0 += tb.x + w0t.x * xv + w1t.x * xm;
        v1 += tb.y + w0t.y * xv + w1t.y * xm;
        v2 += tb.z + w0t.z * xv + w1t.z * xm;
        v3 += tb.w + w0t.w * xv + w1t.w * xm;
        float ig = __builtin_amdgcn_rcpf(1.0f + __expf(-v0));
        float fg = __builtin_amdgcn_rcpf(1.0f + __expf(-v1));
        float gg = 2.0f * __builtin_amdgcn_rcpf(1.0f + __expf(-2.0f * v2)) - 1.0f;
        float og = __builtin_amdgcn_rcpf(1.0f + __expf(-v3));
        float cn = fg * c_reg[mt][nt] + ig * gg;
        c_reg[mt][nt] = cn;
        float th = 2.0f * __builtin_amdgcn_rcpf(1.0f + __expf(-2.0f * cn)) - 1.0f;
        float hn = og * th;
        if (last) {
          out[((size_t)f * B_N + brow) * H_N + q * 128 + rg] = hn;
        } else {
          uint32_t sw = (uint32_t)((brow & 7) << 4);
          *(__bf16*)(lds_stage + ((uint32_t)(brow * 256 + rg * 2) ^ sw)) = (__bf16)hn;
        }
      }
    }
    if (last) break;

    __syncthreads();  // lds_stage complete; all lds_h reads done

    // ---- publish own slice (16 KB) + write it into lds_h own quarter ----
    {
      __bf16* dstbuf = hx + ((size_t)((t + 1) & 1)) * hxstride + hxfeat;
      uint32_t b = tid >> 3;
      uint32_t off = (tid & 7) * 32;
      uint32_t sw = (b & 7) << 4;
      u32x4 u0 = *(const u32x4*)(lds_stage + ((b * 256 + off) ^ sw));
      u32x4 u1 = *(const u32x4*)(lds_stage + ((b * 256 + off + 16) ^ sw));
      unsigned char* dp = (unsigned char*)dstbuf + b * 1024 + q * 256 + off;
      if (fastpath) {
        asm volatile("global_store_dwordx4 %0, %1, off sc0" ::"v"(dp), "v"(u0) : "memory");
        asm volatile("global_store_dwordx4 %0, %1, off sc0" ::"v"(dp + 16), "v"(u1) : "memory");
        asm volatile("s_waitcnt vmcnt(0)" ::: "memory");
      } else {
        *(u32x4*)(dp) = u0;
        *(u32x4*)(dp + 16) = u1;
      }
      uint32_t hb = b * 1024 + q * 256 + off;
      *(u32x4*)(lds_h + (hb ^ sw)) = u0;
      *(u32x4*)(lds_h + ((hb + 16) ^ sw)) = u1;
    }
    __syncthreads();  // all publishes drained to L2

    // ---- 4-WG rendezvous; next step's streamed prologue overlaps the wait ----
    if (tid == 0) {
      unsigned int* bp = barr + f * T_N + t;
      if (fastpath)
        __hip_atomic_fetch_add(bp, 1u, __ATOMIC_RELAXED, __HIP_MEMORY_SCOPE_AGENT);
      else
        __hip_atomic_fetch_add(bp, 1u, __ATOMIC_RELEASE, __HIP_MEMORY_SCOPE_AGENT);
    }
    // prologue for step t+1 in ITS order: positions 0..2 -> ks (pos+par4n)&7
    LOAD_SLOT(0, (0 + par4n) & 7);
    LOAD_SLOT(1, (1 + par4n) & 7);
    LOAD_SLOT(2, (2 + par4n) & 7);
    if (tid == 0) {
      unsigned int* bp = barr + f * T_N + t;
      unsigned int it = 0;
      while (__hip_atomic_load(bp, __ATOMIC_RELAXED, __HIP_MEMORY_SCOPE_AGENT) < 4u) {
        __builtin_amdgcn_s_sleep(1);
        if (++it > 4000000u) break;  // bail -> wrong answer instead of hang
      }
      if (!fastpath)
        (void)__hip_atomic_load(bp, __ATOMIC_ACQUIRE, __HIP_MEMORY_SCOPE_AGENT);
    }
    __syncthreads();

    // ---- stage the 3 partner quarters (48 KB) into lds_h ----
    if (fastpath) {
      asm volatile("buffer_inv sc0" ::: "memory");  // vL1-only invalidate
    }
    {
      const unsigned char* src =
          (const unsigned char*)(hx + ((size_t)((t + 1) & 1)) * hxstride + hxfeat);
      uint32_t b = tid >> 3;
      uint32_t off = (tid & 7) * 32;
      uint32_t sw = (b & 7) << 4;
#pragma unroll
      for (int qq = 0; qq < 4; ++qq) {
        if (qq == q) continue;
        uint32_t gb = b * 1024 + qq * 256 + off;
        uint4 u0 = *(const uint4*)(src + gb);
        uint4 u1 = *(const uint4*)(src + gb + 16);
        *(uint4*)(lds_h + (gb ^ sw)) = u0;
        *(uint4*)(lds_h + ((gb + 16) ^ sw)) = u1;
      }
    }
    __syncthreads();
  }
#undef LOAD_SLOT
#undef READ_A
#undef MFMA_W
#undef STATIC_V
#undef STATIC_L
#undef STREAM
}

// ---------------- launch ----------------
extern "C" void kernel_launch(void* const* d_in, const int* in_sizes, int n_in,
                              void* d_out, int out_size, void* d_ws, size_t ws_size,
                              hipStream_t stream) {
  const float* tf = (const float*)d_in[0];
  const float* tm = (const float*)d_in[1];
  const float* h0 = (const float*)d_in[2];
  const float* c0 = (const float*)d_in[3];
  const float* Wih = (const float*)d_in[4];
  const float* Whh = (const float*)d_in[5];
  const float* bih = (const float*)d_in[6];
  const float* bhh = (const float*)d_in[7];
  float* out = (float*)d_out;

  const size_t WP_BYTES = (size_t)8388608 * 16;             // 134,217,728
  const size_t XP_BYTES = (size_t)T_N * F_N * B_N * 2 * 4;  // 16,777,216
  const size_t HX_BYTES = (size_t)2 * F_N * B_N * H_N * 2;  // 8,388,608
  const size_t BARR_BYTES = (size_t)F_N * T_N * 4;          // 65,536
  const size_t MAP_BYTES = 1024;
  if (ws_size < WP_BYTES + XP_BYTES + HX_BYTES + BARR_BYTES + MAP_BYTES) return;

  char* ws = (char*)d_ws;
  __bf16* Wp = (__bf16*)ws;
  float* xp = (float*)(ws + WP_BYTES);
  __bf16* hx = (__bf16*)(ws + WP_BYTES + XP_BYTES);
  unsigned int* barr = (unsigned int*)(ws + WP_BYTES + XP_BYTES + HX_BYTES);
  unsigned int* xcdmap = (unsigned int*)(ws + WP_BYTES + XP_BYTES + HX_BYTES + BARR_BYTES);

  hipMemsetAsync(barr, 0, BARR_BYTES + MAP_BYTES, stream);
  pack_x_kernel<<<(T_N * B_N * F_N + 255) / 256, 256, 0, stream>>>(tf, tm, xp);
  pack_h0_kernel<<<(F_N * B_N * H_N + 255) / 256, 256, 0, stream>>>(h0, hx);
  pack_w_kernel<<<8388608 / 256, 256, 0, stream>>>(Whh, Wp);
  lstm_main<<<256, 512, 0, stream>>>(c0, Wp, Wih, bih, bhh, xp, hx, barr, xcdmap, out);
}